// Round 15
// baseline (291.957 us; speedup 1.0000x reference)
//
#include <hip/hip_runtime.h>
#include <hip/hip_bf16.h>

#define D 64
#define KCODES 1024
// Error budget (OFFSET=2048 pins distances in [2048,4096), ULP<=4.9e-4):
// split residual <=0.025 + key-quant 63*ULP<=0.015 + MFMA rounding <=0.004
// => eps ~0.044, 2*eps ~0.09 < MARGIN 0.25. Near-ties rescored exactly.
// Scheme absmax=0.0 on HW (rounds 3/5/6/10/13).
#define MARGIN 0.25f
#define OFFSET 2048.0f

typedef __attribute__((ext_vector_type(8))) short bf16x8;
typedef __attribute__((ext_vector_type(4))) float f32x4;

__device__ __forceinline__ unsigned short f2bf(float f) {
    union { __hip_bfloat16 h; unsigned short s; } cv;
    cv.h = __float2bfloat16(f);
    return cv.s;
}
__device__ __forceinline__ float bf2f(unsigned short v) {
    union { unsigned short s; __hip_bfloat16 h; } cv;
    cv.s = v;
    return __bfloat162float(cv.h);
}

__device__ __forceinline__ void stage16(const void* g, void* l) {
    __builtin_amdgcn_global_load_lds(
        (const __attribute__((address_space(1))) void*)g,
        (__attribute__((address_space(3))) void*)l, 16, 0, 0);
}

// k0: unchanged (measured, absmax 0.0).
__global__ __launch_bounds__(256) void prep_kernel(
    const float* __restrict__ emb, float* __restrict__ e2, float* __restrict__ e2b,
    unsigned short* __restrict__ ehi, unsigned short* __restrict__ elo,
    unsigned int* __restrict__ counter) {
    int t = blockIdx.x * 256 + threadIdx.x;
    if (t == 0) *counter = 0u;
    if (t < KCODES) {
        const float4* ep = (const float4*)(emb + (size_t)t * D);
        float s0 = 0.f, s1 = 0.f, s2 = 0.f, s3 = 0.f;
#pragma unroll
        for (int i = 0; i < 16; ++i) {
            float4 v = ep[i];
            s0 = fmaf(v.x, v.x, s0);
            s1 = fmaf(v.y, v.y, s1);
            s2 = fmaf(v.z, v.z, s2);
            s3 = fmaf(v.w, v.w, s3);
        }
        float s = (s0 + s1) + (s2 + s3);
        e2[t] = s;
        e2b[t] = s + OFFSET;
    }
    float v = emb[t];
    unsigned short h = f2bf(v);
    ehi[t] = h;
    elo[t] = f2bf(v - bf2f(h));
}

// k1: TRUE TLP DOUBLING. Post-mortem of r13: r10 (4blk x 4w) and r13
// (8blk x 2w) were BOTH 16 waves/CU -> identical 71us / 29% MfmaUtil /
// ~30% occupancy. Barrier-group count and block shape proven irrelevant;
// waves/CU never actually changed. Now: 4 waves SHARE one 2x8KB double
// buffer -> 256-thread blocks (4 waves x 32 rows = 128 rows), 2-tile groups,
// grid 1024. LDS 16.9KB/block -> 8 blocks/CU (thread-capped) x 4 waves =
// 32 waves/CU = 8 waves/SIMD (HW max). Legal only because VGPR=64
// (m69 occupancy cliff); __launch_bounds__(256,8) pins it. Per-wave
// numerics/swizzle/key-pack byte-identical to the HW-validated r13 path.
__global__ __launch_bounds__(256, 8) void vq_mfma_kernel(
    const float* __restrict__ x, const float* __restrict__ emb,
    const float* __restrict__ e2b, const unsigned short* __restrict__ ehi,
    const unsigned short* __restrict__ elo, float* __restrict__ out_q,
    float* __restrict__ out_idx, float* __restrict__ out_loss,
    unsigned int* __restrict__ counter, int* __restrict__ flaglist, int flag_cap) {
    __shared__ float4 lds4[2][512];   // 2 x 8KB group buffers (shared by 4 waves)
    __shared__ int s_bi[128];
    char* ldsc = (char*)&lds4[0][0];
    const int tid = threadIdx.x;      // 0..255
    const int lane = tid & 63;
    const int wave = __builtin_amdgcn_readfirstlane(tid >> 6);   // 0..3
    const int quad = lane >> 4;
    const int l15 = lane & 15;
    const int rowBase = blockIdx.x * 128 + wave * 32;

    // A fragments: 2 rowsets x 16 rows, pre-scaled by -2 (exact), bf16 hi/lo.
    bf16x8 ah[2][2], al[2][2];
#pragma unroll
    for (int rs = 0; rs < 2; ++rs) {
        const float* xr = x + (size_t)(rowBase + rs * 16 + l15) * D;
#pragma unroll
        for (int c = 0; c < 2; ++c) {
            const float4* p = (const float4*)(xr + c * 32 + quad * 8);
            float4 f0 = p[0], f1 = p[1];
            float f[8] = {f0.x, f0.y, f0.z, f0.w, f1.x, f1.y, f1.z, f1.w};
            bf16x8 h, l;
#pragma unroll
            for (int j = 0; j < 8; ++j) {
                float v = -2.0f * f[j];
                unsigned short hu = f2bf(v);
                h[j] = (short)hu;
                l[j] = (short)f2bf(v - bf2f(hu));   // exact (Sterbenz)
            }
            ah[rs][c] = h;
            al[rs][c] = l;
        }
    }

    // DMA staging: group = 8KB = [h:2][row:32][slot:8] 16B units, LDS-linear.
    // 256 threads stage 2 units each: li = i*256 + tid (i=0..1) — bijective.
    // h=li>>8, row=(li>>3)&31, sl=li&7. Global src pre-swizzled (rule #21):
    // physical slot sl of row r fed from logical slot sl^(r&7); ds_read XOR
    // unchanged (HW-validated r13). LDS dest: buf + i*4096 + wave*1024
    // (+lane*16 by HW) = unit i*256 + wave*64 + lane = li. Bijective.
    const unsigned short* gs[2];
#pragma unroll
    for (int i = 0; i < 2; ++i) {
        int li = i * 256 + tid;
        int h = li >> 8, row = (li >> 3) & 31, sl = li & 7;
        gs[i] = (h ? elo : ehi) + row * 64 + (sl ^ (row & 7)) * 8;
    }
    char* wbase = ldsc + wave * 1024;  // + buf*8192 + i*4096 (+lane*16 by HW)

    // ds_read offsets (swizzled): group row = tg*16 + l15; (tg*16)&7==0 so
    // XOR key stays l15&7. hi at rb, lo at rb+4096; tile stride 2048.
    const int s7 = l15 & 7;
    const int rdA0 = l15 * 128 + ((quad ^ s7) << 4);
    const int rdB0 = l15 * 128 + (((quad + 4) ^ s7) << 4);

    unsigned int m1[2][4], m2[2][4];
#pragma unroll
    for (int rs = 0; rs < 2; ++rs)
#pragma unroll
        for (int r = 0; r < 4; ++r) { m1[rs][r] = 0xFFFFFFFFu; m2[rs][r] = 0xFFFFFFFFu; }

    // Prologue: DMA group 0 -> buf0; group-0 e2b.
#pragma unroll
    for (int i = 0; i < 2; ++i) stage16(gs[i], wbase + i * 4096);
    float e2v0 = e2b[l15];
    float e2v1 = e2b[16 + l15];
    __syncthreads();

#pragma unroll 1
    for (int g = 0; g < 32; ++g) {
        float e2n0, e2n1;
        if (g < 31) {
            char* wb = wbase + (((g + 1) & 1) << 13);
#pragma unroll
            for (int i = 0; i < 2; ++i)
                stage16(gs[i] + (size_t)(g + 1) * 2048, wb + i * 4096);
            e2n0 = e2b[(g + 1) * 32 + l15];
            e2n1 = e2b[(g + 1) * 32 + 16 + l15];
        }
        __builtin_amdgcn_sched_barrier(0);
        const char* rb = ldsc + ((g & 1) << 13);
#pragma unroll
        for (int tg = 0; tg < 2; ++tg) {
            bf16x8 bh0 = *(const bf16x8*)(rb + tg * 2048 + rdA0);
            bf16x8 bh1 = *(const bf16x8*)(rb + tg * 2048 + rdB0);
            bf16x8 bl0 = *(const bf16x8*)(rb + 4096 + tg * 2048 + rdA0);
            bf16x8 bl1 = *(const bf16x8*)(rb + 4096 + tg * 2048 + rdB0);
            const unsigned tt = (unsigned)(g * 2 + tg);
            const float ev = tg ? e2v1 : e2v0;
            f32x4 c0 = {ev, ev, ev, ev};
#pragma unroll
            for (int rs = 0; rs < 2; ++rs) {
                // Single 6-MFMA chain per rowset (r3/r10/r13-validated):
                // hi*hi + lo*hi + hi*lo per K-chunk; lo*lo omitted.
                f32x4 acc = c0;
                acc = __builtin_amdgcn_mfma_f32_16x16x32_bf16(ah[rs][0], bh0, acc, 0, 0, 0);
                acc = __builtin_amdgcn_mfma_f32_16x16x32_bf16(al[rs][0], bh0, acc, 0, 0, 0);
                acc = __builtin_amdgcn_mfma_f32_16x16x32_bf16(ah[rs][0], bl0, acc, 0, 0, 0);
                acc = __builtin_amdgcn_mfma_f32_16x16x32_bf16(ah[rs][1], bh1, acc, 0, 0, 0);
                acc = __builtin_amdgcn_mfma_f32_16x16x32_bf16(al[rs][1], bh1, acc, 0, 0, 0);
                acc = __builtin_amdgcn_mfma_f32_16x16x32_bf16(ah[rs][1], bl1, acc, 0, 0, 0);
#pragma unroll
                for (int r = 0; r < 4; ++r) {
                    unsigned k = (__float_as_uint(acc[r]) & 0xFFFFFFC0u) | tt;
                    unsigned nm2;
                    asm("v_med3_u32 %0, %1, %2, %3"
                        : "=v"(nm2)
                        : "v"(m1[rs][r]), "v"(m2[rs][r]), "v"(k));
                    m2[rs][r] = nm2;
                    m1[rs][r] = (k < m1[rs][r]) ? k : m1[rs][r];
                }
            }
        }
        if (g < 31) { e2v0 = e2n0; e2v1 = e2n1; }
        __syncthreads();
    }

    // Cross-lane merge over the 16 code-lanes; winner lane via ballot.
#pragma unroll
    for (int rs = 0; rs < 2; ++rs)
#pragma unroll
        for (int r = 0; r < 4; ++r) {
            unsigned v1 = m1[rs][r], v2 = m2[rs][r];
            const unsigned my1 = v1;
#pragma unroll
            for (int mask = 1; mask < 16; mask <<= 1) {
                unsigned o1 = __shfl_xor(v1, mask);
                unsigned o2 = __shfl_xor(v2, mask);
                unsigned hi = v1 > o1 ? v1 : o1;
                unsigned lo2 = v2 < o2 ? v2 : o2;
                v2 = lo2 < hi ? lo2 : hi;
                v1 = v1 < o1 ? v1 : o1;
            }
            unsigned long long bal = __ballot(my1 == v1);
            int winl = __ffsll((bal >> (quad * 16)) & 0xFFFFull) - 1;
            int code = (int)(v1 & 63u) * 16 + winl;
            if (l15 == 0) {
                int lrow = wave * 32 + rs * 16 + quad * 4 + r;
                s_bi[lrow] = code;
                float f1 = __uint_as_float(v1 & 0xFFFFFFC0u);
                float f2 = __uint_as_float(v2 & 0xFFFFFFC0u);
                if (f2 - f1 < MARGIN) {
                    unsigned slot = atomicAdd(counter, 1u);
                    if (slot < (unsigned)flag_cap) flaglist[slot] = blockIdx.x * 128 + lrow;
                }
            }
        }
    __syncthreads();

    // Fused epilogue: arithmetic verbatim (one row/thread, first 128 threads).
    if (tid < 128) {
        const int row = blockIdx.x * 128 + tid;
        const int bi = s_bi[tid];
        const float4* qp = (const float4*)(emb + (size_t)bi * D);
        const float4* xp = (const float4*)(x + (size_t)row * D);
        float4* oq = (float4*)(out_q + (size_t)row * D);
        float l0 = 0.f, l1 = 0.f, l2 = 0.f, l3 = 0.f;
#pragma unroll
        for (int i = 0; i < 16; ++i) {
            float4 q = qp[i];
            float4 xv = xp[i];
            float a0 = q.x - xv.x, a1 = q.y - xv.y, a2 = q.z - xv.z, a3 = q.w - xv.w;
            l0 = fmaf(a0, a0, l0);
            l1 = fmaf(a1, a1, l1);
            l2 = fmaf(a2, a2, l2);
            l3 = fmaf(a3, a3, l3);
            float4 o;
            o.x = xv.x + a0;
            o.y = xv.y + a1;
            o.z = xv.z + a2;
            o.w = xv.w + a3;
            oq[i] = o;
        }
        float s = (l0 + l1) + (l2 + l3);
        out_idx[row] = (float)bi;
        out_loss[row] = s + 0.25f * s;
    }
}

// k2: byte-identical to the round-10/13 measured version.
__global__ __launch_bounds__(256) void rescore_kernel(
    const float* __restrict__ x, const float* __restrict__ emb,
    const float* __restrict__ e2, float* __restrict__ out_q,
    float* __restrict__ out_idx, float* __restrict__ out_loss,
    const unsigned int* __restrict__ counter, const int* __restrict__ flaglist,
    int flag_cap) {
    __shared__ float s_x[8][64];
    __shared__ int s_rows[8];
    __shared__ float s_wd[8][4];
    __shared__ int s_wi[8][4];
    __shared__ float s_a[4][64];
    unsigned int n = *counter;
    if (n > (unsigned)flag_cap) n = (unsigned)flag_cap;
    const int tid = threadIdx.x;
    const int lane = tid & 63;
    const int wv = tid >> 6;
    for (unsigned int b = blockIdx.x; b * 8u < n; b += gridDim.x) {
        const unsigned base = b * 8u;
        unsigned nbu = n - base;
        if (nbu > 8u) nbu = 8u;
        const int nb = (int)nbu;
        if (tid < 8) s_rows[tid] = flaglist[base + (tid < nb ? tid : 0)];
        __syncthreads();
        if (tid < 128) {
            int r = tid >> 4, q4 = tid & 15;
            ((float4*)&s_x[r][0])[q4] = ((const float4*)(x + (size_t)s_rows[r] * D))[q4];
        }
        __syncthreads();

        float bd_[8];
        int bi_[8];
#pragma unroll
        for (int r = 0; r < 8; ++r) { bd_[r] = 3.4e38f; bi_[r] = 0; }
#pragma unroll 1
        for (int kk = 0; kk < 4; ++kk) {
            const int k = tid + kk * 256;
            const float4* ekp = (const float4*)(emb + (size_t)k * D);
            float d0[8], d1[8], d2[8], d3[8];
#pragma unroll
            for (int r = 0; r < 8; ++r) { d0[r] = 0.f; d1[r] = 0.f; d2[r] = 0.f; d3[r] = 0.f; }
#pragma unroll 1
            for (int i = 0; i < 16; ++i) {
                float4 ev = ekp[i];
#pragma unroll
                for (int r = 0; r < 8; ++r) {
                    float4 xv = ((const float4*)&s_x[r][0])[i];
                    d0[r] = fmaf(xv.x, ev.x, d0[r]);
                    d1[r] = fmaf(xv.y, ev.y, d1[r]);
                    d2[r] = fmaf(xv.z, ev.z, d2[r]);
                    d3[r] = fmaf(xv.w, ev.w, d3[r]);
                }
            }
            float e2k = e2[k];
#pragma unroll
            for (int r = 0; r < 8; ++r) {
                float dist = fmaf(-2.0f, (d0[r] + d1[r]) + (d2[r] + d3[r]), e2k);
                if (dist < bd_[r]) { bd_[r] = dist; bi_[r] = k; }
            }
        }
#pragma unroll
        for (int r = 0; r < 8; ++r) {
            float v = bd_[r];
            int ix = bi_[r];
#pragma unroll
            for (int mask = 1; mask < 64; mask <<= 1) {
                float ov = __shfl_xor(v, mask);
                int oi = __shfl_xor(ix, mask);
                bool tk = (ov < v) || (ov == v && oi < ix);
                v = tk ? ov : v;
                ix = tk ? oi : ix;
            }
            if (lane == 0) { s_wd[r][wv] = v; s_wi[r][wv] = ix; }
        }
        __syncthreads();
        if (tid < 8) {
            float v = s_wd[tid][0];
            int ix = s_wi[tid][0];
#pragma unroll
            for (int w = 1; w < 4; ++w) {
                float ov = s_wd[tid][w];
                int oi = s_wi[tid][w];
                bool tk = (ov < v) || (ov == v && oi < ix);
                v = tk ? ov : v;
                ix = tk ? oi : ix;
            }
            s_wi[tid][0] = ix;
        }
        __syncthreads();
#pragma unroll
        for (int pass = 0; pass < 2; ++pass) {
            const int rloc = pass * 4 + wv;
            const int row = s_rows[rloc];
            const int fbi = s_wi[rloc][0];
            const float xe = s_x[rloc][lane];
            const float a = emb[(size_t)fbi * D + lane] - xe;
            if (rloc < nb) out_q[(size_t)row * D + lane] = xe + a;
            s_a[wv][lane] = a * a;
            __syncthreads();
            if (lane == 0 && rloc < nb) {
                float l0 = 0.f, l1 = 0.f, l2 = 0.f, l3 = 0.f;
                for (int i2 = 0; i2 < 16; ++i2) {
                    l0 += s_a[wv][4 * i2 + 0];
                    l1 += s_a[wv][4 * i2 + 1];
                    l2 += s_a[wv][4 * i2 + 2];
                    l3 += s_a[wv][4 * i2 + 3];
                }
                float s = (l0 + l1) + (l2 + l3);
                out_loss[row] = s + 0.25f * s;
                out_idx[row] = (float)fbi;
            }
            __syncthreads();
        }
    }
}

extern "C" void kernel_launch(void* const* d_in, const int* in_sizes, int n_in,
                              void* d_out, int out_size, void* d_ws, size_t ws_size,
                              hipStream_t stream) {
    const float* x = (const float*)d_in[0];     // [B,T,D] fp32
    const float* emb = (const float*)d_in[1];   // [K,D] fp32
    const int nrows = in_sizes[0] / D;          // 131072

    float* out_q = (float*)d_out;
    float* out_idx = out_q + (size_t)nrows * D;
    float* out_loss = out_idx + nrows;

    // ws: e2 4KB | e2b 4KB | ehi 128KB | elo 128KB | counter 64B | flaglist
    char* ws = (char*)d_ws;
    float* e2 = (float*)ws;
    float* e2b = (float*)(ws + 4096);
    unsigned short* ehi = (unsigned short*)(ws + 8192);
    unsigned short* elo = (unsigned short*)(ws + 8192 + 131072);
    unsigned int* counter = (unsigned int*)(ws + 8192 + 262144);
    int* flaglist = (int*)(ws + 8192 + 262144 + 64);
    long long avail = (long long)ws_size - (8192 + 262144 + 64);
    int flag_cap = (int)(avail / 4);
    if (flag_cap > 16384) flag_cap = 16384;
    if (flag_cap < 1024) flag_cap = 1024;

    prep_kernel<<<(KCODES * D) / 256, 256, 0, stream>>>(emb, e2, e2b, ehi, elo, counter);
    vq_mfma_kernel<<<nrows / 128, 256, 0, stream>>>(x, emb, e2b, ehi, elo, out_q,
                                                    out_idx, out_loss, counter,
                                                    flaglist, flag_cap);
    rescore_kernel<<<1024, 256, 0, stream>>>(x, emb, e2, out_q, out_idx, out_loss,
                                             counter, flaglist, flag_cap);
}

// Round 16
// 172.971 us; speedup vs baseline: 1.6879x; 1.6879x over previous
//
#include <hip/hip_runtime.h>
#include <hip/hip_bf16.h>

#define D 64
#define KCODES 1024
// Error budget (OFFSET=2048 pins distances in [2048,4096), ULP<=4.9e-4):
// split residual <=0.025 + key-quant 63*ULP<=0.015 + MFMA rounding <=0.004
// => eps ~0.044, 2*eps ~0.09 < MARGIN 0.25. Near-ties rescored exactly.
// Scheme absmax=0.0 on HW (rounds 3/5/6/10/13/15).
#define MARGIN 0.25f
#define OFFSET 2048.0f

typedef __attribute__((ext_vector_type(8))) short bf16x8;
typedef __attribute__((ext_vector_type(4))) float f32x4;

__device__ __forceinline__ unsigned short f2bf(float f) {
    union { __hip_bfloat16 h; unsigned short s; } cv;
    cv.h = __float2bfloat16(f);
    return cv.s;
}
__device__ __forceinline__ float bf2f(unsigned short v) {
    union { unsigned short s; __hip_bfloat16 h; } cv;
    cv.s = v;
    return __bfloat162float(cv.h);
}

__device__ __forceinline__ void stage16(const void* g, void* l) {
    __builtin_amdgcn_global_load_lds(
        (const __attribute__((address_space(1))) void*)g,
        (__attribute__((address_space(3))) void*)l, 16, 0, 0);
}

// k0: unchanged (measured, absmax 0.0).
__global__ __launch_bounds__(256) void prep_kernel(
    const float* __restrict__ emb, float* __restrict__ e2, float* __restrict__ e2b,
    unsigned short* __restrict__ ehi, unsigned short* __restrict__ elo,
    unsigned int* __restrict__ counter) {
    int t = blockIdx.x * 256 + threadIdx.x;
    if (t == 0) *counter = 0u;
    if (t < KCODES) {
        const float4* ep = (const float4*)(emb + (size_t)t * D);
        float s0 = 0.f, s1 = 0.f, s2 = 0.f, s3 = 0.f;
#pragma unroll
        for (int i = 0; i < 16; ++i) {
            float4 v = ep[i];
            s0 = fmaf(v.x, v.x, s0);
            s1 = fmaf(v.y, v.y, s1);
            s2 = fmaf(v.z, v.z, s2);
            s3 = fmaf(v.w, v.w, s3);
        }
        float s = (s0 + s1) + (s2 + s3);
        e2[t] = s;
        e2b[t] = s + OFFSET;
    }
    float v = emb[t];
    unsigned short h = f2bf(v);
    ehi[t] = h;
    elo[t] = f2bf(v - bf2f(h));
}

// k1: ROUND-16 — r15 geometry (4 waves share 2x8KB dbuf, 256 thr, grid 1024,
// target 8 blk/CU = 32 waves/CU) with the launch-bounds spill FIXED.
// r15 post-mortem: __launch_bounds__(256,8) forced a 64-reg unified-file
// budget -> allocator emitted a 32-VGPR body and scratch-spilled the
// A-fragments (FETCH 266MB / WRITE 390MB of scratch, MfmaUtil 0.9%, 205us).
// r13's identical per-wave body compiled to EXACTLY 64 VGPR under a 128 cap,
// and at VGPR=64 the HW already supports 8 waves/SIMD (m69: halves only
// ABOVE 64). So (256,4) caps at 128, compiler lands ~64, no spill, and
// 32 waves/CU follows from actual VGPR + LDS 16.9KB + thread cap.
__global__ __launch_bounds__(256, 4) void vq_mfma_kernel(
    const float* __restrict__ x, const float* __restrict__ emb,
    const float* __restrict__ e2b, const unsigned short* __restrict__ ehi,
    const unsigned short* __restrict__ elo, float* __restrict__ out_q,
    float* __restrict__ out_idx, float* __restrict__ out_loss,
    unsigned int* __restrict__ counter, int* __restrict__ flaglist, int flag_cap) {
    __shared__ float4 lds4[2][512];   // 2 x 8KB group buffers (shared by 4 waves)
    __shared__ int s_bi[128];
    char* ldsc = (char*)&lds4[0][0];
    const int tid = threadIdx.x;      // 0..255
    const int lane = tid & 63;
    const int wave = __builtin_amdgcn_readfirstlane(tid >> 6);   // 0..3
    const int quad = lane >> 4;
    const int l15 = lane & 15;
    const int rowBase = blockIdx.x * 128 + wave * 32;

    // A fragments: 2 rowsets x 16 rows, pre-scaled by -2 (exact), bf16 hi/lo.
    bf16x8 ah[2][2], al[2][2];
#pragma unroll
    for (int rs = 0; rs < 2; ++rs) {
        const float* xr = x + (size_t)(rowBase + rs * 16 + l15) * D;
#pragma unroll
        for (int c = 0; c < 2; ++c) {
            const float4* p = (const float4*)(xr + c * 32 + quad * 8);
            float4 f0 = p[0], f1 = p[1];
            float f[8] = {f0.x, f0.y, f0.z, f0.w, f1.x, f1.y, f1.z, f1.w};
            bf16x8 h, l;
#pragma unroll
            for (int j = 0; j < 8; ++j) {
                float v = -2.0f * f[j];
                unsigned short hu = f2bf(v);
                h[j] = (short)hu;
                l[j] = (short)f2bf(v - bf2f(hu));   // exact (Sterbenz)
            }
            ah[rs][c] = h;
            al[rs][c] = l;
        }
    }

    // DMA staging: group = 8KB = [h:2][row:32][slot:8] 16B units, LDS-linear.
    // 256 threads stage 2 units each: li = i*256 + tid (i=0..1) — bijective.
    // h=li>>8, row=(li>>3)&31, sl=li&7. Global src pre-swizzled (rule #21):
    // physical slot sl of row r fed from logical slot sl^(r&7); ds_read XOR
    // unchanged (HW-validated r13). LDS dest: buf + i*4096 + wave*1024
    // (+lane*16 by HW) = unit i*256 + wave*64 + lane = li. Bijective.
    const unsigned short* gs[2];
#pragma unroll
    for (int i = 0; i < 2; ++i) {
        int li = i * 256 + tid;
        int h = li >> 8, row = (li >> 3) & 31, sl = li & 7;
        gs[i] = (h ? elo : ehi) + row * 64 + (sl ^ (row & 7)) * 8;
    }
    char* wbase = ldsc + wave * 1024;  // + buf*8192 + i*4096 (+lane*16 by HW)

    // ds_read offsets (swizzled): group row = tg*16 + l15; (tg*16)&7==0 so
    // XOR key stays l15&7. hi at rb, lo at rb+4096; tile stride 2048.
    const int s7 = l15 & 7;
    const int rdA0 = l15 * 128 + ((quad ^ s7) << 4);
    const int rdB0 = l15 * 128 + (((quad + 4) ^ s7) << 4);

    unsigned int m1[2][4], m2[2][4];
#pragma unroll
    for (int rs = 0; rs < 2; ++rs)
#pragma unroll
        for (int r = 0; r < 4; ++r) { m1[rs][r] = 0xFFFFFFFFu; m2[rs][r] = 0xFFFFFFFFu; }

    // Prologue: DMA group 0 -> buf0; group-0 e2b.
#pragma unroll
    for (int i = 0; i < 2; ++i) stage16(gs[i], wbase + i * 4096);
    float e2v0 = e2b[l15];
    float e2v1 = e2b[16 + l15];
    __syncthreads();

#pragma unroll 1
    for (int g = 0; g < 32; ++g) {
        float e2n0, e2n1;
        if (g < 31) {
            char* wb = wbase + (((g + 1) & 1) << 13);
#pragma unroll
            for (int i = 0; i < 2; ++i)
                stage16(gs[i] + (size_t)(g + 1) * 2048, wb + i * 4096);
            e2n0 = e2b[(g + 1) * 32 + l15];
            e2n1 = e2b[(g + 1) * 32 + 16 + l15];
        }
        __builtin_amdgcn_sched_barrier(0);
        const char* rb = ldsc + ((g & 1) << 13);
#pragma unroll
        for (int tg = 0; tg < 2; ++tg) {
            bf16x8 bh0 = *(const bf16x8*)(rb + tg * 2048 + rdA0);
            bf16x8 bh1 = *(const bf16x8*)(rb + tg * 2048 + rdB0);
            bf16x8 bl0 = *(const bf16x8*)(rb + 4096 + tg * 2048 + rdA0);
            bf16x8 bl1 = *(const bf16x8*)(rb + 4096 + tg * 2048 + rdB0);
            const unsigned tt = (unsigned)(g * 2 + tg);
            const float ev = tg ? e2v1 : e2v0;
            f32x4 c0 = {ev, ev, ev, ev};
#pragma unroll
            for (int rs = 0; rs < 2; ++rs) {
                // Single 6-MFMA chain per rowset (r3/r10/r13-validated):
                // hi*hi + lo*hi + hi*lo per K-chunk; lo*lo omitted.
                f32x4 acc = c0;
                acc = __builtin_amdgcn_mfma_f32_16x16x32_bf16(ah[rs][0], bh0, acc, 0, 0, 0);
                acc = __builtin_amdgcn_mfma_f32_16x16x32_bf16(al[rs][0], bh0, acc, 0, 0, 0);
                acc = __builtin_amdgcn_mfma_f32_16x16x32_bf16(ah[rs][0], bl0, acc, 0, 0, 0);
                acc = __builtin_amdgcn_mfma_f32_16x16x32_bf16(ah[rs][1], bh1, acc, 0, 0, 0);
                acc = __builtin_amdgcn_mfma_f32_16x16x32_bf16(al[rs][1], bh1, acc, 0, 0, 0);
                acc = __builtin_amdgcn_mfma_f32_16x16x32_bf16(ah[rs][1], bl1, acc, 0, 0, 0);
#pragma unroll
                for (int r = 0; r < 4; ++r) {
                    unsigned k = (__float_as_uint(acc[r]) & 0xFFFFFFC0u) | tt;
                    unsigned nm2;
                    asm("v_med3_u32 %0, %1, %2, %3"
                        : "=v"(nm2)
                        : "v"(m1[rs][r]), "v"(m2[rs][r]), "v"(k));
                    m2[rs][r] = nm2;
                    m1[rs][r] = (k < m1[rs][r]) ? k : m1[rs][r];
                }
            }
        }
        if (g < 31) { e2v0 = e2n0; e2v1 = e2n1; }
        __syncthreads();
    }

    // Cross-lane merge over the 16 code-lanes; winner lane via ballot.
#pragma unroll
    for (int rs = 0; rs < 2; ++rs)
#pragma unroll
        for (int r = 0; r < 4; ++r) {
            unsigned v1 = m1[rs][r], v2 = m2[rs][r];
            const unsigned my1 = v1;
#pragma unroll
            for (int mask = 1; mask < 16; mask <<= 1) {
                unsigned o1 = __shfl_xor(v1, mask);
                unsigned o2 = __shfl_xor(v2, mask);
                unsigned hi = v1 > o1 ? v1 : o1;
                unsigned lo2 = v2 < o2 ? v2 : o2;
                v2 = lo2 < hi ? lo2 : hi;
                v1 = v1 < o1 ? v1 : o1;
            }
            unsigned long long bal = __ballot(my1 == v1);
            int winl = __ffsll((bal >> (quad * 16)) & 0xFFFFull) - 1;
            int code = (int)(v1 & 63u) * 16 + winl;
            if (l15 == 0) {
                int lrow = wave * 32 + rs * 16 + quad * 4 + r;
                s_bi[lrow] = code;
                float f1 = __uint_as_float(v1 & 0xFFFFFFC0u);
                float f2 = __uint_as_float(v2 & 0xFFFFFFC0u);
                if (f2 - f1 < MARGIN) {
                    unsigned slot = atomicAdd(counter, 1u);
                    if (slot < (unsigned)flag_cap) flaglist[slot] = blockIdx.x * 128 + lrow;
                }
            }
        }
    __syncthreads();

    // Fused epilogue: arithmetic verbatim (one row/thread, first 128 threads).
    if (tid < 128) {
        const int row = blockIdx.x * 128 + tid;
        const int bi = s_bi[tid];
        const float4* qp = (const float4*)(emb + (size_t)bi * D);
        const float4* xp = (const float4*)(x + (size_t)row * D);
        float4* oq = (float4*)(out_q + (size_t)row * D);
        float l0 = 0.f, l1 = 0.f, l2 = 0.f, l3 = 0.f;
#pragma unroll
        for (int i = 0; i < 16; ++i) {
            float4 q = qp[i];
            float4 xv = xp[i];
            float a0 = q.x - xv.x, a1 = q.y - xv.y, a2 = q.z - xv.z, a3 = q.w - xv.w;
            l0 = fmaf(a0, a0, l0);
            l1 = fmaf(a1, a1, l1);
            l2 = fmaf(a2, a2, l2);
            l3 = fmaf(a3, a3, l3);
            float4 o;
            o.x = xv.x + a0;
            o.y = xv.y + a1;
            o.z = xv.z + a2;
            o.w = xv.w + a3;
            oq[i] = o;
        }
        float s = (l0 + l1) + (l2 + l3);
        out_idx[row] = (float)bi;
        out_loss[row] = s + 0.25f * s;
    }
}

// k2: byte-identical to the round-10/13 measured version.
__global__ __launch_bounds__(256) void rescore_kernel(
    const float* __restrict__ x, const float* __restrict__ emb,
    const float* __restrict__ e2, float* __restrict__ out_q,
    float* __restrict__ out_idx, float* __restrict__ out_loss,
    const unsigned int* __restrict__ counter, const int* __restrict__ flaglist,
    int flag_cap) {
    __shared__ float s_x[8][64];
    __shared__ int s_rows[8];
    __shared__ float s_wd[8][4];
    __shared__ int s_wi[8][4];
    __shared__ float s_a[4][64];
    unsigned int n = *counter;
    if (n > (unsigned)flag_cap) n = (unsigned)flag_cap;
    const int tid = threadIdx.x;
    const int lane = tid & 63;
    const int wv = tid >> 6;
    for (unsigned int b = blockIdx.x; b * 8u < n; b += gridDim.x) {
        const unsigned base = b * 8u;
        unsigned nbu = n - base;
        if (nbu > 8u) nbu = 8u;
        const int nb = (int)nbu;
        if (tid < 8) s_rows[tid] = flaglist[base + (tid < nb ? tid : 0)];
        __syncthreads();
        if (tid < 128) {
            int r = tid >> 4, q4 = tid & 15;
            ((float4*)&s_x[r][0])[q4] = ((const float4*)(x + (size_t)s_rows[r] * D))[q4];
        }
        __syncthreads();

        float bd_[8];
        int bi_[8];
#pragma unroll
        for (int r = 0; r < 8; ++r) { bd_[r] = 3.4e38f; bi_[r] = 0; }
#pragma unroll 1
        for (int kk = 0; kk < 4; ++kk) {
            const int k = tid + kk * 256;
            const float4* ekp = (const float4*)(emb + (size_t)k * D);
            float d0[8], d1[8], d2[8], d3[8];
#pragma unroll
            for (int r = 0; r < 8; ++r) { d0[r] = 0.f; d1[r] = 0.f; d2[r] = 0.f; d3[r] = 0.f; }
#pragma unroll 1
            for (int i = 0; i < 16; ++i) {
                float4 ev = ekp[i];
#pragma unroll
                for (int r = 0; r < 8; ++r) {
                    float4 xv = ((const float4*)&s_x[r][0])[i];
                    d0[r] = fmaf(xv.x, ev.x, d0[r]);
                    d1[r] = fmaf(xv.y, ev.y, d1[r]);
                    d2[r] = fmaf(xv.z, ev.z, d2[r]);
                    d3[r] = fmaf(xv.w, ev.w, d3[r]);
                }
            }
            float e2k = e2[k];
#pragma unroll
            for (int r = 0; r < 8; ++r) {
                float dist = fmaf(-2.0f, (d0[r] + d1[r]) + (d2[r] + d3[r]), e2k);
                if (dist < bd_[r]) { bd_[r] = dist; bi_[r] = k; }
            }
        }
#pragma unroll
        for (int r = 0; r < 8; ++r) {
            float v = bd_[r];
            int ix = bi_[r];
#pragma unroll
            for (int mask = 1; mask < 64; mask <<= 1) {
                float ov = __shfl_xor(v, mask);
                int oi = __shfl_xor(ix, mask);
                bool tk = (ov < v) || (ov == v && oi < ix);
                v = tk ? ov : v;
                ix = tk ? oi : ix;
            }
            if (lane == 0) { s_wd[r][wv] = v; s_wi[r][wv] = ix; }
        }
        __syncthreads();
        if (tid < 8) {
            float v = s_wd[tid][0];
            int ix = s_wi[tid][0];
#pragma unroll
            for (int w = 1; w < 4; ++w) {
                float ov = s_wd[tid][w];
                int oi = s_wi[tid][w];
                bool tk = (ov < v) || (ov == v && oi < ix);
                v = tk ? ov : v;
                ix = tk ? oi : ix;
            }
            s_wi[tid][0] = ix;
        }
        __syncthreads();
#pragma unroll
        for (int pass = 0; pass < 2; ++pass) {
            const int rloc = pass * 4 + wv;
            const int row = s_rows[rloc];
            const int fbi = s_wi[rloc][0];
            const float xe = s_x[rloc][lane];
            const float a = emb[(size_t)fbi * D + lane] - xe;
            if (rloc < nb) out_q[(size_t)row * D + lane] = xe + a;
            s_a[wv][lane] = a * a;
            __syncthreads();
            if (lane == 0 && rloc < nb) {
                float l0 = 0.f, l1 = 0.f, l2 = 0.f, l3 = 0.f;
                for (int i2 = 0; i2 < 16; ++i2) {
                    l0 += s_a[wv][4 * i2 + 0];
                    l1 += s_a[wv][4 * i2 + 1];
                    l2 += s_a[wv][4 * i2 + 2];
                    l3 += s_a[wv][4 * i2 + 3];
                }
                float s = (l0 + l1) + (l2 + l3);
                out_loss[row] = s + 0.25f * s;
                out_idx[row] = (float)fbi;
            }
            __syncthreads();
        }
    }
}

extern "C" void kernel_launch(void* const* d_in, const int* in_sizes, int n_in,
                              void* d_out, int out_size, void* d_ws, size_t ws_size,
                              hipStream_t stream) {
    const float* x = (const float*)d_in[0];     // [B,T,D] fp32
    const float* emb = (const float*)d_in[1];   // [K,D] fp32
    const int nrows = in_sizes[0] / D;          // 131072

    float* out_q = (float*)d_out;
    float* out_idx = out_q + (size_t)nrows * D;
    float* out_loss = out_idx + nrows;

    // ws: e2 4KB | e2b 4KB | ehi 128KB | elo 128KB | counter 64B | flaglist
    char* ws = (char*)d_ws;
    float* e2 = (float*)ws;
    float* e2b = (float*)(ws + 4096);
    unsigned short* ehi = (unsigned short*)(ws + 8192);
    unsigned short* elo = (unsigned short*)(ws + 8192 + 131072);
    unsigned int* counter = (unsigned int*)(ws + 8192 + 262144);
    int* flaglist = (int*)(ws + 8192 + 262144 + 64);
    long long avail = (long long)ws_size - (8192 + 262144 + 64);
    int flag_cap = (int)(avail / 4);
    if (flag_cap > 16384) flag_cap = 16384;
    if (flag_cap < 1024) flag_cap = 1024;

    prep_kernel<<<(KCODES * D) / 256, 256, 0, stream>>>(emb, e2, e2b, ehi, elo, counter);
    vq_mfma_kernel<<<nrows / 128, 256, 0, stream>>>(x, emb, e2b, ehi, elo, out_q,
                                                    out_idx, out_loss, counter,
                                                    flaglist, flag_cap);
    rescore_kernel<<<1024, 256, 0, stream>>>(x, emb, e2, out_q, out_idx, out_loss,
                                             counter, flaglist, flag_cap);
}

// Round 22
// 170.674 us; speedup vs baseline: 1.7106x; 1.0135x over previous
//
#include <hip/hip_runtime.h>
#include <hip/hip_bf16.h>

#define D 64
#define KCODES 1024
// Error budget (OFFSET=2048 pins distances in [2048,4096), ULP<=4.9e-4):
// split residual <=0.025 + key-quant 63*ULP<=0.015 + MFMA rounding <=0.004
// => eps ~0.044, 2*eps ~0.09 < MARGIN 0.25. Near-ties rescored exactly.
// Scheme absmax=0.0 on HW (rounds 3/5/6/10/13/15/16).
#define MARGIN 0.25f
#define OFFSET 2048.0f

typedef __attribute__((ext_vector_type(8))) short bf16x8;
typedef __attribute__((ext_vector_type(4))) float f32x4;

__device__ __forceinline__ unsigned short f2bf(float f) {
    union { __hip_bfloat16 h; unsigned short s; } cv;
    cv.h = __float2bfloat16(f);
    return cv.s;
}
__device__ __forceinline__ float bf2f(unsigned short v) {
    union { unsigned short s; __hip_bfloat16 h; } cv;
    cv.s = v;
    return __bfloat162float(cv.h);
}

__device__ __forceinline__ void stage16(const void* g, void* l) {
    __builtin_amdgcn_global_load_lds(
        (const __attribute__((address_space(1))) void*)g,
        (__attribute__((address_space(3))) void*)l, 16, 0, 0);
}

// k0: unchanged (measured, absmax 0.0).
__global__ __launch_bounds__(256) void prep_kernel(
    const float* __restrict__ emb, float* __restrict__ e2, float* __restrict__ e2b,
    unsigned short* __restrict__ ehi, unsigned short* __restrict__ elo,
    unsigned int* __restrict__ counter) {
    int t = blockIdx.x * 256 + threadIdx.x;
    if (t == 0) *counter = 0u;
    if (t < KCODES) {
        const float4* ep = (const float4*)(emb + (size_t)t * D);
        float s0 = 0.f, s1 = 0.f, s2 = 0.f, s3 = 0.f;
#pragma unroll
        for (int i = 0; i < 16; ++i) {
            float4 v = ep[i];
            s0 = fmaf(v.x, v.x, s0);
            s1 = fmaf(v.y, v.y, s1);
            s2 = fmaf(v.z, v.z, s2);
            s3 = fmaf(v.w, v.w, s3);
        }
        float s = (s0 + s1) + (s2 + s3);
        e2[t] = s;
        e2b[t] = s + OFFSET;
    }
    float v = emb[t];
    unsigned short h = f2bf(v);
    ehi[t] = h;
    elo[t] = f2bf(v - bf2f(h));
}

// k1: T4 COUNTED-VMCNT PIPELINE (race-fixed). r16 diagnosis: MfmaUtil=29%
// = 725 TF = the 2-phase stage->drain->barrier structural ceiling
// (m233/m230); counted vmcnt is the proven fix (m218 +38-73%).
// vmcnt is PER-WAVE, and each wave's compute reads OTHER waves' staged
// data, so the vmcnt that retires group N's own loads must come BEFORE the
// barrier that publishes N (retire-then-publish). Phase g: issue(g+3) ->
// compute(g) [published by prev barrier] -> vmcnt(4) [retires own g+1;
// g+2,g+3 stay in flight ACROSS the barrier] -> s_barrier [publishes g+1].
// Prologue: e2b + groups 0-2, vmcnt(4) (retires e2b+group0), barrier.
// Tail: compute(29), vmcnt(0), barrier, compute(30,31). Overwrite-safety:
// issue for buf[(g+3)&3] (holds g-1) follows the phase-(g-1) barrier;
// g-1's ds_reads retired pre-barrier. sched_barrier(0) after each waitcnt
// (rule #18). Numerics byte-identical to the absmax-0.0-validated path.
// Deadlock-checked: uniform barrier counts (1+29+1) across all waves.
__global__ __launch_bounds__(256, 4) void vq_mfma_kernel(
    const float* __restrict__ x, const float* __restrict__ emb,
    const float* __restrict__ e2b, const unsigned short* __restrict__ ehi,
    const unsigned short* __restrict__ elo, float* __restrict__ out_q,
    float* __restrict__ out_idx, float* __restrict__ out_loss,
    unsigned int* __restrict__ counter, int* __restrict__ flaglist, int flag_cap) {
    __shared__ float4 lds4[4][512];                 // 4 x 8KB group buffers
    __shared__ __align__(16) float s_e2b[KCODES];   // 4KB biased norms (DMA'd once)
    __shared__ int s_bi[128];
    char* ldsc = (char*)&lds4[0][0];
    const int tid = threadIdx.x;      // 0..255
    const int lane = tid & 63;
    const int wave = __builtin_amdgcn_readfirstlane(tid >> 6);   // 0..3
    const int quad = lane >> 4;
    const int l15 = lane & 15;
    const int rowBase = blockIdx.x * 128 + wave * 32;

    // A fragments: 2 rowsets x 16 rows, pre-scaled by -2 (exact), bf16 hi/lo.
    bf16x8 ah[2][2], al[2][2];
#pragma unroll
    for (int rs = 0; rs < 2; ++rs) {
        const float* xr = x + (size_t)(rowBase + rs * 16 + l15) * D;
#pragma unroll
        for (int c = 0; c < 2; ++c) {
            const float4* p = (const float4*)(xr + c * 32 + quad * 8);
            float4 f0 = p[0], f1 = p[1];
            float f[8] = {f0.x, f0.y, f0.z, f0.w, f1.x, f1.y, f1.z, f1.w};
            bf16x8 h, l;
#pragma unroll
            for (int j = 0; j < 8; ++j) {
                float v = -2.0f * f[j];
                unsigned short hu = f2bf(v);
                h[j] = (short)hu;
                l[j] = (short)f2bf(v - bf2f(hu));   // exact (Sterbenz)
            }
            ah[rs][c] = h;
            al[rs][c] = l;
        }
    }

    // DMA staging map (r13/r16-validated): group = 8KB = [h:2][row:32][slot:8]
    // 16B units. 256 threads x 2 units: li = i*256 + tid. Global src
    // pre-swizzled (rule #21): physical slot sl of row r fed from logical
    // sl^(r&7). LDS dest buf + i*4096 + wave*1024 (+lane*16 by HW) = li.
    const unsigned short* gs[2];
#pragma unroll
    for (int i = 0; i < 2; ++i) {
        int li = i * 256 + tid;
        int h = li >> 8, row = (li >> 3) & 31, sl = li & 7;
        gs[i] = (h ? elo : ehi) + row * 64 + (sl ^ (row & 7)) * 8;
    }
    char* wbase = ldsc + wave * 1024;  // + buf*8192 + i*4096 (+lane*16 by HW)

    // ds_read offsets (swizzled), unchanged (HW-validated).
    const int s7 = l15 & 7;
    const int rdA0 = l15 * 128 + ((quad ^ s7) << 4);
    const int rdB0 = l15 * 128 + (((quad + 4) ^ s7) << 4);

    unsigned int m1[2][4], m2[2][4];
#pragma unroll
    for (int rs = 0; rs < 2; ++rs)
#pragma unroll
        for (int r = 0; r < 4; ++r) { m1[rs][r] = 0xFFFFFFFFu; m2[rs][r] = 0xFFFFFFFFu; }

    // Prologue: DMA e2b (oldest in FIFO) + groups 0,1,2 -> bufs 0,1,2.
    // vmcnt(4) retires e2b + group 0; barrier publishes them. Groups 1,2
    // stay in flight across the barrier.
    stage16(e2b + 4 * tid, (char*)s_e2b + wave * 1024);
#pragma unroll
    for (int gg = 0; gg < 3; ++gg)
#pragma unroll
        for (int i = 0; i < 2; ++i)
            stage16(gs[i] + (size_t)gg * 2048, wbase + gg * 8192 + i * 4096);
    asm volatile("s_waitcnt vmcnt(4)" ::: "memory");
    __builtin_amdgcn_sched_barrier(0);
    __builtin_amdgcn_s_barrier();

    auto compute_group = [&](int g) {
        const char* rb = ldsc + (g & 3) * 8192;
        float e2v0 = s_e2b[g * 32 + l15];
        float e2v1 = s_e2b[g * 32 + 16 + l15];
#pragma unroll
        for (int tg = 0; tg < 2; ++tg) {
            bf16x8 bh0 = *(const bf16x8*)(rb + tg * 2048 + rdA0);
            bf16x8 bh1 = *(const bf16x8*)(rb + tg * 2048 + rdB0);
            bf16x8 bl0 = *(const bf16x8*)(rb + 4096 + tg * 2048 + rdA0);
            bf16x8 bl1 = *(const bf16x8*)(rb + 4096 + tg * 2048 + rdB0);
            const unsigned tt = (unsigned)(g * 2 + tg);
            const float ev = tg ? e2v1 : e2v0;
            f32x4 c0 = {ev, ev, ev, ev};
#pragma unroll
            for (int rs = 0; rs < 2; ++rs) {
                // Single 6-MFMA chain (validated): hi*hi + lo*hi + hi*lo.
                f32x4 acc = c0;
                acc = __builtin_amdgcn_mfma_f32_16x16x32_bf16(ah[rs][0], bh0, acc, 0, 0, 0);
                acc = __builtin_amdgcn_mfma_f32_16x16x32_bf16(al[rs][0], bh0, acc, 0, 0, 0);
                acc = __builtin_amdgcn_mfma_f32_16x16x32_bf16(ah[rs][0], bl0, acc, 0, 0, 0);
                acc = __builtin_amdgcn_mfma_f32_16x16x32_bf16(ah[rs][1], bh1, acc, 0, 0, 0);
                acc = __builtin_amdgcn_mfma_f32_16x16x32_bf16(al[rs][1], bh1, acc, 0, 0, 0);
                acc = __builtin_amdgcn_mfma_f32_16x16x32_bf16(ah[rs][1], bl1, acc, 0, 0, 0);
#pragma unroll
                for (int r = 0; r < 4; ++r) {
                    unsigned k = (__float_as_uint(acc[r]) & 0xFFFFFFC0u) | tt;
                    unsigned nm2;
                    asm("v_med3_u32 %0, %1, %2, %3"
                        : "=v"(nm2)
                        : "v"(m1[rs][r]), "v"(m2[rs][r]), "v"(k));
                    m2[rs][r] = nm2;
                    m1[rs][r] = (k < m1[rs][r]) ? k : m1[rs][r];
                }
            }
        }
    };

    // Main loop (retire-then-publish): issue g+3; compute g (published by
    // the previous barrier); vmcnt(4) retires OWN g+1 loads (g+2,g+3 remain
    // in flight ACROSS the barrier); barrier publishes g+1 for phase g+1.
#pragma unroll 1
    for (int g = 0; g < 29; ++g) {
#pragma unroll
        for (int i = 0; i < 2; ++i)
            stage16(gs[i] + (size_t)(g + 3) * 2048, wbase + ((g + 3) & 3) * 8192 + i * 4096);
        compute_group(g);
        asm volatile("s_waitcnt vmcnt(4)" ::: "memory");
        __builtin_amdgcn_sched_barrier(0);
        __builtin_amdgcn_s_barrier();
    }
    // Tail: 29 is published; retire+publish 30,31 once, then compute them.
    compute_group(29);
    asm volatile("s_waitcnt vmcnt(0)" ::: "memory");
    __builtin_amdgcn_sched_barrier(0);
    __builtin_amdgcn_s_barrier();
    compute_group(30);
    compute_group(31);

    // Cross-lane merge over the 16 code-lanes; winner lane via ballot.
#pragma unroll
    for (int rs = 0; rs < 2; ++rs)
#pragma unroll
        for (int r = 0; r < 4; ++r) {
            unsigned v1 = m1[rs][r], v2 = m2[rs][r];
            const unsigned my1 = v1;
#pragma unroll
            for (int mask = 1; mask < 16; mask <<= 1) {
                unsigned o1 = __shfl_xor(v1, mask);
                unsigned o2 = __shfl_xor(v2, mask);
                unsigned hi = v1 > o1 ? v1 : o1;
                unsigned lo2 = v2 < o2 ? v2 : o2;
                v2 = lo2 < hi ? lo2 : hi;
                v1 = v1 < o1 ? v1 : o1;
            }
            unsigned long long bal = __ballot(my1 == v1);
            int winl = __ffsll((bal >> (quad * 16)) & 0xFFFFull) - 1;
            int code = (int)(v1 & 63u) * 16 + winl;
            if (l15 == 0) {
                int lrow = wave * 32 + rs * 16 + quad * 4 + r;
                s_bi[lrow] = code;
                float f1 = __uint_as_float(v1 & 0xFFFFFFC0u);
                float f2 = __uint_as_float(v2 & 0xFFFFFFC0u);
                if (f2 - f1 < MARGIN) {
                    unsigned slot = atomicAdd(counter, 1u);
                    if (slot < (unsigned)flag_cap) flaglist[slot] = blockIdx.x * 128 + lrow;
                }
            }
        }
    __syncthreads();

    // Fused epilogue: arithmetic verbatim (one row/thread, first 128 threads).
    if (tid < 128) {
        const int row = blockIdx.x * 128 + tid;
        const int bi = s_bi[tid];
        const float4* qp = (const float4*)(emb + (size_t)bi * D);
        const float4* xp = (const float4*)(x + (size_t)row * D);
        float4* oq = (float4*)(out_q + (size_t)row * D);
        float l0 = 0.f, l1 = 0.f, l2 = 0.f, l3 = 0.f;
#pragma unroll
        for (int i = 0; i < 16; ++i) {
            float4 q = qp[i];
            float4 xv = xp[i];
            float a0 = q.x - xv.x, a1 = q.y - xv.y, a2 = q.z - xv.z, a3 = q.w - xv.w;
            l0 = fmaf(a0, a0, l0);
            l1 = fmaf(a1, a1, l1);
            l2 = fmaf(a2, a2, l2);
            l3 = fmaf(a3, a3, l3);
            float4 o;
            o.x = xv.x + a0;
            o.y = xv.y + a1;
            o.z = xv.z + a2;
            o.w = xv.w + a3;
            oq[i] = o;
        }
        float s = (l0 + l1) + (l2 + l3);
        out_idx[row] = (float)bi;
        out_loss[row] = s + 0.25f * s;
    }
}

// k2: byte-identical to the round-10/13/16 measured version.
__global__ __launch_bounds__(256) void rescore_kernel(
    const float* __restrict__ x, const float* __restrict__ emb,
    const float* __restrict__ e2, float* __restrict__ out_q,
    float* __restrict__ out_idx, float* __restrict__ out_loss,
    const unsigned int* __restrict__ counter, const int* __restrict__ flaglist,
    int flag_cap) {
    __shared__ float s_x[8][64];
    __shared__ int s_rows[8];
    __shared__ float s_wd[8][4];
    __shared__ int s_wi[8][4];
    __shared__ float s_a[4][64];
    unsigned int n = *counter;
    if (n > (unsigned)flag_cap) n = (unsigned)flag_cap;
    const int tid = threadIdx.x;
    const int lane = tid & 63;
    const int wv = tid >> 6;
    for (unsigned int b = blockIdx.x; b * 8u < n; b += gridDim.x) {
        const unsigned base = b * 8u;
        unsigned nbu = n - base;
        if (nbu > 8u) nbu = 8u;
        const int nb = (int)nbu;
        if (tid < 8) s_rows[tid] = flaglist[base + (tid < nb ? tid : 0)];
        __syncthreads();
        if (tid < 128) {
            int r = tid >> 4, q4 = tid & 15;
            ((float4*)&s_x[r][0])[q4] = ((const float4*)(x + (size_t)s_rows[r] * D))[q4];
        }
        __syncthreads();

        float bd_[8];
        int bi_[8];
#pragma unroll
        for (int r = 0; r < 8; ++r) { bd_[r] = 3.4e38f; bi_[r] = 0; }
#pragma unroll 1
        for (int kk = 0; kk < 4; ++kk) {
            const int k = tid + kk * 256;
            const float4* ekp = (const float4*)(emb + (size_t)k * D);
            float d0[8], d1[8], d2[8], d3[8];
#pragma unroll
            for (int r = 0; r < 8; ++r) { d0[r] = 0.f; d1[r] = 0.f; d2[r] = 0.f; d3[r] = 0.f; }
#pragma unroll 1
            for (int i = 0; i < 16; ++i) {
                float4 ev = ekp[i];
#pragma unroll
                for (int r = 0; r < 8; ++r) {
                    float4 xv = ((const float4*)&s_x[r][0])[i];
                    d0[r] = fmaf(xv.x, ev.x, d0[r]);
                    d1[r] = fmaf(xv.y, ev.y, d1[r]);
                    d2[r] = fmaf(xv.z, ev.z, d2[r]);
                    d3[r] = fmaf(xv.w, ev.w, d3[r]);
                }
            }
            float e2k = e2[k];
#pragma unroll
            for (int r = 0; r < 8; ++r) {
                float dist = fmaf(-2.0f, (d0[r] + d1[r]) + (d2[r] + d3[r]), e2k);
                if (dist < bd_[r]) { bd_[r] = dist; bi_[r] = k; }
            }
        }
#pragma unroll
        for (int r = 0; r < 8; ++r) {
            float v = bd_[r];
            int ix = bi_[r];
#pragma unroll
            for (int mask = 1; mask < 64; mask <<= 1) {
                float ov = __shfl_xor(v, mask);
                int oi = __shfl_xor(ix, mask);
                bool tk = (ov < v) || (ov == v && oi < ix);
                v = tk ? ov : v;
                ix = tk ? oi : ix;
            }
            if (lane == 0) { s_wd[r][wv] = v; s_wi[r][wv] = ix; }
        }
        __syncthreads();
        if (tid < 8) {
            float v = s_wd[tid][0];
            int ix = s_wi[tid][0];
#pragma unroll
            for (int w = 1; w < 4; ++w) {
                float ov = s_wd[tid][w];
                int oi = s_wi[tid][w];
                bool tk = (ov < v) || (ov == v && oi < ix);
                v = tk ? ov : v;
                ix = tk ? oi : ix;
            }
            s_wi[tid][0] = ix;
        }
        __syncthreads();
#pragma unroll
        for (int pass = 0; pass < 2; ++pass) {
            const int rloc = pass * 4 + wv;
            const int row = s_rows[rloc];
            const int fbi = s_wi[rloc][0];
            const float xe = s_x[rloc][lane];
            const float a = emb[(size_t)fbi * D + lane] - xe;
            if (rloc < nb) out_q[(size_t)row * D + lane] = xe + a;
            s_a[wv][lane] = a * a;
            __syncthreads();
            if (lane == 0 && rloc < nb) {
                float l0 = 0.f, l1 = 0.f, l2 = 0.f, l3 = 0.f;
                for (int i2 = 0; i2 < 16; ++i2) {
                    l0 += s_a[wv][4 * i2 + 0];
                    l1 += s_a[wv][4 * i2 + 1];
                    l2 += s_a[wv][4 * i2 + 2];
                    l3 += s_a[wv][4 * i2 + 3];
                }
                float s = (l0 + l1) + (l2 + l3);
                out_loss[row] = s + 0.25f * s;
                out_idx[row] = (float)fbi;
            }
            __syncthreads();
        }
    }
}

extern "C" void kernel_launch(void* const* d_in, const int* in_sizes, int n_in,
                              void* d_out, int out_size, void* d_ws, size_t ws_size,
                              hipStream_t stream) {
    const float* x = (const float*)d_in[0];     // [B,T,D] fp32
    const float* emb = (const float*)d_in[1];   // [K,D] fp32
    const int nrows = in_sizes[0] / D;          // 131072

    float* out_q = (float*)d_out;
    float* out_idx = out_q + (size_t)nrows * D;
    float* out_loss = out_idx + nrows;

    // ws: e2 4KB | e2b 4KB | ehi 128KB | elo 128KB | counter 64B | flaglist
    char* ws = (char*)d_ws;
    float* e2 = (float*)ws;
    float* e2b = (float*)(ws + 4096);
    unsigned short* ehi = (unsigned short*)(ws + 8192);
    unsigned short* elo = (unsigned short*)(ws + 8192 + 131072);
    unsigned int* counter = (unsigned int*)(ws + 8192 + 262144);
    int* flaglist = (int*)(ws + 8192 + 262144 + 64);
    long long avail = (long long)ws_size - (8192 + 262144 + 64);
    int flag_cap = (int)(avail / 4);
    if (flag_cap > 16384) flag_cap = 16384;
    if (flag_cap < 1024) flag_cap = 1024;

    prep_kernel<<<(KCODES * D) / 256, 256, 0, stream>>>(emb, e2, e2b, ehi, elo, counter);
    vq_mfma_kernel<<<nrows / 128, 256, 0, stream>>>(x, emb, e2b, ehi, elo, out_q,
                                                    out_idx, out_loss, counter,
                                                    flaglist, flag_cap);
    rescore_kernel<<<1024, 256, 0, stream>>>(x, emb, e2, out_q, out_idx, out_loss,
                                             counter, flaglist, flag_cap);
}